// Round 8
// baseline (324.246 us; speedup 1.0000x reference)
//
#include <hip/hip_runtime.h>
#include <hip/hip_bf16.h>
#include <math.h>

#define Bn 32
#define Nn 2048
#define Cc 256
#define Sn 128
#define KK 16
#define H 128
#define OUTC 79
#define ODIM 124
#define KP1 288  // layer-1 K padded: 256 features + 3 xyz + 29 zeros

typedef __attribute__((ext_vector_type(8))) short short8;
typedef __attribute__((ext_vector_type(4))) float f32x4;
typedef unsigned long long ull;

__device__ __constant__ float MEANF[30] = {
    0.76584f, 1.398258f, 0.472728f,
    2.114256f, 1.6203f, 0.927272f,
    0.404671f, 1.071108f, 1.688889f,
    0.591958f, 0.552978f, 0.827272f,
    0.69519f, 1.346299f, 0.736364f,
    0.528526f, 1.002642f, 1.172878f,
    0.500618f, 0.632163f, 0.683424f,
    0.923508f, 1.867419f, 0.845495f,
    0.791118f, 1.279516f, 0.718182f,
    0.699104f, 0.454178f, 0.75625f};

__device__ __forceinline__ unsigned short f2bf(float f) {
    __hip_bfloat16 h = __float2bfloat16(f);
    return *reinterpret_cast<unsigned short*>(&h);
}

__device__ __forceinline__ float w0val(const float* __restrict__ w0, int n, int k) {
    if (k < 256) return w0[(3 + k) * H + n];
    if (k < 259) return w0[(k - 256) * H + n];
    return 0.0f;
}

// butterfly level via ds_swizzle (xor within 32-lane halves), key = (hi,lo) u64, carries xyz
#define BFLY_SWZ(PAT)                                                          \
    {                                                                          \
        const int ohi = __builtin_amdgcn_ds_swizzle(hi, PAT);                  \
        const int olo = __builtin_amdgcn_ds_swizzle(lo, PAT);                  \
        const int oxi = __builtin_amdgcn_ds_swizzle(xi, PAT);                  \
        const int oyi = __builtin_amdgcn_ds_swizzle(yi, PAT);                  \
        const int ozi = __builtin_amdgcn_ds_swizzle(zi, PAT);                  \
        const ull ok = ((ull)(unsigned)ohi << 32) | (unsigned)olo;             \
        const ull ck = ((ull)(unsigned)hi << 32) | (unsigned)lo;               \
        if (ok > ck) { hi = ohi; lo = olo; xi = oxi; yi = oyi; zi = ozi; }     \
    }

// ---------------- fused FPS (blocks 0..31) + transpose + prep ----------------
struct SmemFPS {
    int red[2][4][8];          // per-wave winner: key.hi, key.lo, x, y, z (32B slots, parity dbuf)
    float nx[Sn * 3];          // new_xyz staging
};
struct SmemT {
    float tile[64][33];
};
__global__ __launch_bounds__(256) void fused_front_kernel(
    const float* __restrict__ xyz, const float* __restrict__ features,
    float* __restrict__ new_xyz, unsigned short* __restrict__ fT,
    const float* __restrict__ w0, const float* __restrict__ bb0,
    const float* __restrict__ g0, const float* __restrict__ be0,
    const float* __restrict__ m0, const float* __restrict__ v0,
    const float* __restrict__ w1, const float* __restrict__ bb1,
    const float* __restrict__ g1, const float* __restrict__ be1,
    const float* __restrict__ m1, const float* __restrict__ v1,
    const float* __restrict__ w2, const float* __restrict__ bb2,
    const float* __restrict__ g2, const float* __restrict__ be2,
    const float* __restrict__ m2, const float* __restrict__ v2,
    const float* __restrict__ c1w, const float* __restrict__ c1b,
    const float* __restrict__ g3, const float* __restrict__ be3,
    const float* __restrict__ m3, const float* __restrict__ v3,
    const float* __restrict__ c2w, const float* __restrict__ c2b,
    const float* __restrict__ g4, const float* __restrict__ be4,
    const float* __restrict__ m4, const float* __restrict__ v4,
    const float* __restrict__ c3w, const float* __restrict__ c3b,
    unsigned short* __restrict__ Wf0, unsigned short* __restrict__ Wf1,
    unsigned short* __restrict__ Wf2, unsigned short* __restrict__ Wfc1,
    unsigned short* __restrict__ Wfc2, unsigned short* __restrict__ Wfc3,
    float* __restrict__ scbi, float* __restrict__ scbiH) {
    __shared__ __align__(16) char smem_raw[sizeof(SmemT) > sizeof(SmemFPS) ? sizeof(SmemT)
                                                                           : sizeof(SmemFPS)];
    const int bid = blockIdx.x;
    if (bid >= Bn + 8192) {
        // ---- prep role: fold BN, build FRAGMENT-MAJOR bf16 weights ----
        const int idx = (bid - (Bn + 8192)) * 256 + threadIdx.x;
        if (idx < 4608) {  // layer-1: 9 kc x 8 nt x 64 lanes
            const int kc = idx / 512;
            const int rem = idx & 511;
            const int nt = rem >> 6;
            const int lane = rem & 63;
            const int n = nt * 16 + (lane & 15);
            const int kb = kc * 32 + (lane >> 4) * 8;
            union { unsigned short u[8]; uint4 q; } P;
#pragma unroll
            for (int j = 0; j < 8; j++) P.u[j] = f2bf(w0val(w0, n, kb + j));
            ((uint4*)Wf0)[idx] = P.q;
        }
        if (idx < 2048) {  // 128x128 layers: 4 kc x 8 nt x 64 lanes
            const int kc = idx >> 9;
            const int rem = idx & 511;
            const int nt = rem >> 6;
            const int lane = rem & 63;
            const int n = nt * 16 + (lane & 15);
            const int kb = kc * 32 + (lane >> 4) * 8;
            union { unsigned short u[8]; uint4 q; } P1, P2, P3, P4;
#pragma unroll
            for (int j = 0; j < 8; j++) {
                const int k = kb + j;
                P1.u[j] = f2bf(w1[k * H + n]);
                P2.u[j] = f2bf(w2[k * H + n]);
                P3.u[j] = f2bf(c1w[k * H + n]);
                P4.u[j] = f2bf(c2w[k * H + n]);
            }
            ((uint4*)Wf1)[idx] = P1.q;
            ((uint4*)Wf2)[idx] = P2.q;
            ((uint4*)Wfc1)[idx] = P3.q;
            ((uint4*)Wfc2)[idx] = P4.q;
        }
        if (idx < 1280) {  // c3: 4 kc x 5 nt x 64 lanes (N padded to 80)
            const int kc = idx / 320;
            const int rem = idx % 320;
            const int nt = rem / 64;
            const int lane = rem % 64;
            const int n = nt * 16 + (lane & 15);
            const int kb = kc * 32 + (lane >> 4) * 8;
            union { unsigned short u[8]; uint4 q; } P;
#pragma unroll
            for (int j = 0; j < 8; j++)
                P.u[j] = (n < OUTC) ? f2bf(c3w[(kb + j) * OUTC + n]) : (unsigned short)0;
            ((uint4*)Wfc3)[idx] = P.q;
        }
        if (idx < 128) {
            const float sc1 = g0[idx] / sqrtf(v0[idx] + 1e-5f);
            scbi[0 * 128 + idx] = sc1;
            scbi[1 * 128 + idx] = (bb0[idx] - m0[idx]) * sc1 + be0[idx];
            const float sc2 = g1[idx] / sqrtf(v1[idx] + 1e-5f);
            scbi[2 * 128 + idx] = sc2;
            scbi[3 * 128 + idx] = (bb1[idx] - m1[idx]) * sc2 + be1[idx];
            const float sc3 = g2[idx] / sqrtf(v2[idx] + 1e-5f);
            scbi[4 * 128 + idx] = sc3;
            scbi[5 * 128 + idx] = (bb2[idx] - m2[idx]) * sc3 + be2[idx];
            const float sA = g3[idx] / sqrtf(v3[idx] + 1e-5f);
            scbiH[0 * 128 + idx] = sA;
            scbiH[1 * 128 + idx] = (c1b[idx] - m3[idx]) * sA + be3[idx];
            const float sB = g4[idx] / sqrtf(v4[idx] + 1e-5f);
            scbiH[2 * 128 + idx] = sB;
            scbiH[3 * 128 + idx] = (c2b[idx] - m4[idx]) * sB + be4[idx];
        }
        if (idx < 80) scbiH[512 + idx] = (idx < OUTC) ? c3b[idx] : 0.0f;
        return;
    }
    if (bid >= Bn) {
        // ---- transpose role ----
        SmemT* sm = (SmemT*)smem_raw;
        const int tb = bid - Bn;
        const int b = tb >> 8;
        const int rem = tb & 255;
        const int n0 = (rem & 63) * 32;
        const int c0 = (rem >> 6) * 64;
        const int tx = threadIdx.x & 31;
        const int ty = threadIdx.x >> 5;
        for (int i = ty; i < 64; i += 8)
            sm->tile[i][tx] = features[((size_t)b * Cc + (c0 + i)) * Nn + n0 + tx];
        __syncthreads();
        for (int n = ty; n < 32; n += 8) {
            const float lo2 = sm->tile[tx * 2 + 0][n];
            const float hi2 = sm->tile[tx * 2 + 1][n];
            const unsigned int v = (unsigned int)f2bf(lo2) | ((unsigned int)f2bf(hi2) << 16);
            *reinterpret_cast<unsigned int*>(&fT[((size_t)b * Nn + (n0 + n)) * Cc + c0 + tx * 2]) = v;
        }
        return;
    }
    // ---- FPS role: coords in registers, winner (key,xyz) carried through reduce ----
    {
#pragma clang fp contract(off)
        SmemFPS* sm = (SmemFPS*)smem_raw;
        const int b = bid;
        const int t = threadIdx.x;
        const int lane = t & 63;
        const int wv = t >> 6;
        const int p32addr = ((lane ^ 32) << 2);  // bpermute byte addr for xor-32

        const float* xb = xyz + (size_t)b * Nn * 3;
        float px[8], py[8], pz[8], mind[8];
        int klo[8];
#pragma unroll
        for (int j = 0; j < 8; j++) {
            const int p = wv * 512 + lane + j * 64;
            px[j] = xb[p * 3 + 0];
            py[j] = xb[p * 3 + 1];
            pz[j] = xb[p * 3 + 2];
            mind[j] = 1e10f;
            klo[j] = 2047 - p;
        }
        float lx = xb[0], ly = xb[1], lz = xb[2];

        for (int it = 0; it < Sn; ++it) {
            if (t == 0) {
                sm->nx[it * 3 + 0] = lx;
                sm->nx[it * 3 + 1] = ly;
                sm->nx[it * 3 + 2] = lz;
            }
            // distance update + per-lane tree (key = (dist_bits<<32)|(2047-p), carries coords)
            ull bkey = 0;
            float bx = 0.f, by = 0.f, bz = 0.f;
#pragma unroll
            for (int j = 0; j < 8; j++) {
                const float dx = px[j] - lx;
                const float dy = py[j] - ly;
                const float dz = pz[j] - lz;
                const float dx2 = dx * dx;
                const float dy2 = dy * dy;
                const float dz2 = dz * dz;
                const float s01 = dx2 + dy2;
                const float d = s01 + dz2;
                const float m = fminf(mind[j], d);
                mind[j] = m;
                const ull k = ((ull)__float_as_uint(m) << 32) | (unsigned int)klo[j];
                if (k > bkey) { bkey = k; bx = px[j]; by = py[j]; bz = pz[j]; }
            }
            int hi = (int)(bkey >> 32);
            int lo = (int)(bkey & 0xffffffffull);
            int xi = __float_as_int(bx);
            int yi = __float_as_int(by);
            int zi = __float_as_int(bz);
            // wave butterfly: xor 1,2,4,8,16 via ds_swizzle, xor 32 via ds_bpermute
            BFLY_SWZ(0x041F)
            BFLY_SWZ(0x081F)
            BFLY_SWZ(0x101F)
            BFLY_SWZ(0x201F)
            BFLY_SWZ(0x401F)
            {
                const int ohi = __builtin_amdgcn_ds_bpermute(p32addr, hi);
                const int olo = __builtin_amdgcn_ds_bpermute(p32addr, lo);
                const int oxi = __builtin_amdgcn_ds_bpermute(p32addr, xi);
                const int oyi = __builtin_amdgcn_ds_bpermute(p32addr, yi);
                const int ozi = __builtin_amdgcn_ds_bpermute(p32addr, zi);
                const ull ok = ((ull)(unsigned)ohi << 32) | (unsigned)olo;
                const ull ck = ((ull)(unsigned)hi << 32) | (unsigned)lo;
                if (ok > ck) { hi = ohi; lo = olo; xi = oxi; yi = oyi; zi = ozi; }
            }
            // cross-wave: lane0 writes 20B record, one barrier, all combine 4 slots
            const int par = it & 1;
            if (lane == 0) {
                int* slot = &sm->red[par][wv][0];
                ((int4*)slot)[0] = make_int4(hi, lo, xi, yi);
                slot[4] = zi;
            }
            __syncthreads();
            {
                const int4 s0 = ((const int4*)&sm->red[par][0][0])[0];
                const int4 s1 = ((const int4*)&sm->red[par][1][0])[0];
                const int4 s2 = ((const int4*)&sm->red[par][2][0])[0];
                const int4 s3 = ((const int4*)&sm->red[par][3][0])[0];
                const int z0 = sm->red[par][0][4];
                const int z1 = sm->red[par][1][4];
                const int z2 = sm->red[par][2][4];
                const int z3 = sm->red[par][3][4];
                ull bk = ((ull)(unsigned)s0.x << 32) | (unsigned)s0.y;
                int wxi = s0.z, wyi = s0.w, wzi = z0;
                ull ok = ((ull)(unsigned)s1.x << 32) | (unsigned)s1.y;
                if (ok > bk) { bk = ok; wxi = s1.z; wyi = s1.w; wzi = z1; }
                ok = ((ull)(unsigned)s2.x << 32) | (unsigned)s2.y;
                if (ok > bk) { bk = ok; wxi = s2.z; wyi = s2.w; wzi = z2; }
                ok = ((ull)(unsigned)s3.x << 32) | (unsigned)s3.y;
                if (ok > bk) { bk = ok; wxi = s3.z; wyi = s3.w; wzi = z3; }
                lx = __int_as_float(wxi);
                ly = __int_as_float(wyi);
                lz = __int_as_float(wzi);
            }
        }
        __syncthreads();
        for (int i = t; i < Sn * 3; i += 256)
            new_xyz[(size_t)b * Sn * 3 + i] = sm->nx[i];
    }
}

// ---------------- grouped MLP via MFMA, ball-query fused: one wave per (b,s) ----------------
#define YSTR 136  // LDS row stride in bf16 units (272B, 16B-aligned)
__global__ __launch_bounds__(256) void groupmlp_mfma_kernel(
    const float* __restrict__ xyz, const unsigned short* __restrict__ featT,
    const float* __restrict__ new_xyz,
    const unsigned short* __restrict__ Wf0, const unsigned short* __restrict__ Wf1,
    const unsigned short* __restrict__ Wf2, const float* __restrict__ scbi,
    unsigned short* __restrict__ pooledb) {
    const int wv = threadIdx.x >> 6;
    const int lane = threadIdx.x & 63;
    const int bs = blockIdx.x * 4 + wv;
    const int b = bs >> 7;
    const int mrow = lane & 15;
    const int quad = lane >> 4;

    __shared__ unsigned short ylds_all[4][16 * YSTR];
    __shared__ int sbuf[4][16];
    unsigned short* ylds = &ylds_all[wv][0];

    // ---- fused ball query (first-16 ascending indices within radius) ----
    const float cx = new_xyz[bs * 3 + 0];
    const float cy = new_xyz[bs * 3 + 1];
    const float cz = new_xyz[bs * 3 + 2];
    int basec = 0;
    {
#pragma clang fp contract(off)
        for (int c0 = 0; c0 < Nn && basec < KK; c0 += 64) {
            const int p = c0 + lane;
            const float dx = xyz[((size_t)b * Nn + p) * 3 + 0] - cx;
            const float dy = xyz[((size_t)b * Nn + p) * 3 + 1] - cy;
            const float dz = xyz[((size_t)b * Nn + p) * 3 + 2] - cz;
            const float dx2 = dx * dx;
            const float dy2 = dy * dy;
            const float dz2 = dz * dz;
            const float s01 = dx2 + dy2;
            const float d2 = s01 + dz2;
            const bool q = d2 < 0.09f;
            const ull mask = __ballot(q);
            const int prefix = __popcll(mask & ((1ull << lane) - 1ull));
            const int slot = basec + prefix;
            if (q && slot < KK) sbuf[wv][slot] = p;
            basec += __popcll(mask);
        }
    }
    const int cnt = basec < KK ? basec : KK;
    const int p = sbuf[wv][mrow < cnt ? mrow : 0];

    const short8* arow = reinterpret_cast<const short8*>(featT + ((size_t)(b * Nn + p)) * Cc);

    short8 a1x = {0, 0, 0, 0, 0, 0, 0, 0};
    {
        const float fx = xyz[((size_t)(b * Nn + p)) * 3 + 0];
        const float fy = xyz[((size_t)(b * Nn + p)) * 3 + 1];
        const float fz = xyz[((size_t)(b * Nn + p)) * 3 + 2];
        if (quad == 0) {
            a1x.s0 = (short)f2bf((fx - cx) / 0.3f);
            a1x.s1 = (short)f2bf((fy - cy) / 0.3f);
            a1x.s2 = (short)f2bf((fz - cz) / 0.3f);
        }
    }

    const short8* wf0 = reinterpret_cast<const short8*>(Wf0);
    const short8* wf1 = reinterpret_cast<const short8*>(Wf1);
    const short8* wf2 = reinterpret_cast<const short8*>(Wf2);
    const short8* yv = reinterpret_cast<const short8*>(ylds);

    f32x4 acc[8] = {};

    // ---- layer 1: K = 288 (9 chunks of 32) ----
    {
        short8 acur = arow[quad];
        short8 anxt;
        short8 bcur[8], bnxt[8];
#pragma unroll
        for (int nt = 0; nt < 8; nt++)
            bcur[nt] = wf0[nt * 64 + lane];
        for (int kc = 0; kc < 9; kc++) {
            if (kc < 8) {
                if (kc < 7) anxt = arow[(kc + 1) * 4 + quad];
                else anxt = a1x;
#pragma unroll
                for (int nt = 0; nt < 8; nt++)
                    bnxt[nt] = wf0[((kc + 1) * 8 + nt) * 64 + lane];
            }
#pragma unroll
            for (int nt = 0; nt < 8; nt++)
                acc[nt] = __builtin_amdgcn_mfma_f32_16x16x32_bf16(acur, bcur[nt], acc[nt], 0, 0, 0);
            acur = anxt;
#pragma unroll
            for (int nt = 0; nt < 8; nt++) bcur[nt] = bnxt[nt];
        }
    }
#pragma unroll
    for (int nt = 0; nt < 8; nt++) {
        const int n = nt * 16 + mrow;
        const float sc = scbi[0 * 128 + n];
        const float bi = scbi[1 * 128 + n];
#pragma unroll
        for (int r = 0; r < 4; r++) {
            const float z = fmaxf(acc[nt][r] * sc + bi, 0.0f);
            ylds[(quad * 4 + r) * YSTR + n] = f2bf(z);
        }
    }

    // ---- layer 2: K = 128 (4 chunks) ----
#pragma unroll
    for (int nt = 0; nt < 8; nt++) acc[nt] = (f32x4){0.f, 0.f, 0.f, 0.f};
    {
        short8 acur = yv[mrow * (YSTR / 8) + quad];
        short8 anxt;
        short8 bcur[8], bnxt[8];
#pragma unroll
        for (int nt = 0; nt < 8; nt++)
            bcur[nt] = wf1[nt * 64 + lane];
        for (int kc = 0; kc < 4; kc++) {
            if (kc < 3) {
                anxt = yv[mrow * (YSTR / 8) + (kc + 1) * 4 + quad];
#pragma unroll
                for (int nt = 0; nt < 8; nt++)
                    bnxt[nt] = wf1[((kc + 1) * 8 + nt) * 64 + lane];
            }
#pragma unroll
            for (int nt = 0; nt < 8; nt++)
                acc[nt] = __builtin_amdgcn_mfma_f32_16x16x32_bf16(acur, bcur[nt], acc[nt], 0, 0, 0);
            acur = anxt;
#pragma unroll
            for (int nt = 0; nt < 8; nt++) bcur[nt] = bnxt[nt];
        }
    }
#pragma unroll
    for (int nt = 0; nt < 8; nt++) {
        const int n = nt * 16 + mrow;
        const float sc = scbi[2 * 128 + n];
        const float bi = scbi[3 * 128 + n];
#pragma unroll
        for (int r = 0; r < 4; r++) {
            const float z = fmaxf(acc[nt][r] * sc + bi, 0.0f);
            ylds[(quad * 4 + r) * YSTR + n] = f2bf(z);
        }
    }

    // ---- layer 3: K = 128, then BN+relu+maxpool over m ----
#pragma unroll
    for (int nt = 0; nt < 8; nt++) acc[nt] = (f32x4){0.f, 0.f, 0.f, 0.f};
    {
        short8 acur = yv[mrow * (YSTR / 8) + quad];
        short8 anxt;
        short8 bcur[8], bnxt[8];
#pragma unroll
        for (int nt = 0; nt < 8; nt++)
            bcur[nt] = wf2[nt * 64 + lane];
        for (int kc = 0; kc < 4; kc++) {
            if (kc < 3) {
                anxt = yv[mrow * (YSTR / 8) + (kc + 1) * 4 + quad];
#pragma unroll
                for (int nt = 0; nt < 8; nt++)
                    bnxt[nt] = wf2[((kc + 1) * 8 + nt) * 64 + lane];
            }
#pragma unroll
            for (int nt = 0; nt < 8; nt++)
                acc[nt] = __builtin_amdgcn_mfma_f32_16x16x32_bf16(acur, bcur[nt], acc[nt], 0, 0, 0);
            acur = anxt;
#pragma unroll
            for (int nt = 0; nt < 8; nt++) bcur[nt] = bnxt[nt];
        }
    }
#pragma unroll
    for (int nt = 0; nt < 8; nt++) {
        const int n = nt * 16 + mrow;
        const float sc = scbi[4 * 128 + n];
        const float bi = scbi[5 * 128 + n];
        float vmax = 0.0f;  // relu output >= 0
#pragma unroll
        for (int r = 0; r < 4; r++)
            vmax = fmaxf(vmax, acc[nt][r] * sc + bi);
        vmax = fmaxf(vmax, __shfl_xor(vmax, 16));
        vmax = fmaxf(vmax, __shfl_xor(vmax, 32));
        if (quad == 0) pooledb[(size_t)bs * H + n] = f2bf(vmax);
    }
}

// ---------------- FC head via MFMA: one wave per 16 proposals + fused decode ----------------
__global__ __launch_bounds__(64) void head_mfma_kernel(
    const unsigned short* __restrict__ pooledb, const float* __restrict__ new_xyz,
    const unsigned short* __restrict__ Wfc1, const unsigned short* __restrict__ Wfc2,
    const unsigned short* __restrict__ Wfc3, const float* __restrict__ scbiH,
    float* __restrict__ out) {
    const int lane = threadIdx.x;
    const int row0 = blockIdx.x * 16;
    const int mrow = lane & 15;
    const int quad = lane >> 4;

    __shared__ unsigned short ylds[16 * YSTR];
    __shared__ float flds[16 * 84];

    const short8* ar = reinterpret_cast<const short8*>(pooledb + (size_t)(row0 + mrow) * H);
    const short8* w1h = reinterpret_cast<const short8*>(Wfc1);
    const short8* w2h = reinterpret_cast<const short8*>(Wfc2);
    const short8* w3h = reinterpret_cast<const short8*>(Wfc3);
    const short8* yv = reinterpret_cast<const short8*>(ylds);

    // ---- layer A ----
    f32x4 acc[8] = {};
#pragma unroll
    for (int kc = 0; kc < 4; kc++) {
        const short8 a = ar[kc * 4 + quad];
#pragma unroll
        for (int nt = 0; nt < 8; nt++) {
            const short8 bf = w1h[(kc * 8 + nt) * 64 + lane];
            acc[nt] = __builtin_amdgcn_mfma_f32_16x16x32_bf16(a, bf, acc[nt], 0, 0, 0);
        }
    }
#pragma unroll
    for (int nt = 0; nt < 8; nt++) {
        const int n = nt * 16 + mrow;
        const float sc = scbiH[0 * 128 + n];
        const float bi = scbiH[1 * 128 + n];
#pragma unroll
        for (int r = 0; r < 4; r++) {
            const float z = fmaxf(acc[nt][r] * sc + bi, 0.0f);
            ylds[(quad * 4 + r) * YSTR + n] = f2bf(z);
        }
    }

    // ---- layer B ----
#pragma unroll
    for (int nt = 0; nt < 8; nt++) acc[nt] = (f32x4){0.f, 0.f, 0.f, 0.f};
#pragma unroll
    for (int kc = 0; kc < 4; kc++) {
        const short8 a = yv[mrow * (YSTR / 8) + kc * 4 + quad];
#pragma unroll
        for (int nt = 0; nt < 8; nt++) {
            const short8 bf = w2h[(kc * 8 + nt) * 64 + lane];
            acc[nt] = __builtin_amdgcn_mfma_f32_16x16x32_bf16(a, bf, acc[nt], 0, 0, 0);
        }
    }
#pragma unroll
    for (int nt = 0; nt < 8; nt++) {
        const int n = nt * 16 + mrow;
        const float sc = scbiH[2 * 128 + n];
        const float bi = scbiH[3 * 128 + n];
#pragma unroll
        for (int r = 0; r < 4; r++) {
            const float z = fmaxf(acc[nt][r] * sc + bi, 0.0f);
            ylds[(quad * 4 + r) * YSTR + n] = f2bf(z);
        }
    }

    // ---- layer C: N=80 (col 79 = pad) ----
    f32x4 acc3[5] = {};
#pragma unroll
    for (int kc = 0; kc < 4; kc++) {
        const short8 a = yv[mrow * (YSTR / 8) + kc * 4 + quad];
#pragma unroll
        for (int nt = 0; nt < 5; nt++) {
            const short8 bf = w3h[(kc * 5 + nt) * 64 + lane];
            acc3[nt] = __builtin_amdgcn_mfma_f32_16x16x32_bf16(a, bf, acc3[nt], 0, 0, 0);
        }
    }
#pragma unroll
    for (int nt = 0; nt < 5; nt++) {
        const int n = nt * 16 + mrow;
        const float bi = scbiH[512 + n];
#pragma unroll
        for (int r = 0; r < 4; r++)
            flds[(quad * 4 + r) * 84 + n] = acc3[nt][r] + bi;
    }

    // ---- fused decode ----
    for (int m = 0; m < 16; m++) {
        const int row = row0 + m;
        const float* net = &flds[m * 84];
        const float* nz = new_xyz + (size_t)row * 3;
#pragma unroll
        for (int jj = 0; jj < 2; jj++) {
            const int j = lane + jj * 64;
            if (j < ODIM) {
                float val;
                if (j < 3) val = nz[j];
                else if (j < 5) val = net[j - 3];
                else if (j < 8) val = nz[j - 5] + net[2 + (j - 5)];
                else if (j < 20) val = net[5 + (j - 8)];
                else if (j < 32) val = net[17 + (j - 20)];
                else if (j < 44) val = net[17 + (j - 32)] * (float)(3.14159265358979323846 / 12.0);
                else if (j < 54) val = net[29 + (j - 44)];
                else if (j < 84) val = net[39 + (j - 54)];
                else if (j < 114) val = net[39 + (j - 84)] * MEANF[j - 84];
                else val = net[69 + (j - 114)];
                out[(size_t)row * ODIM + j] = val;
            }
        }
    }
}

extern "C" void kernel_launch(void* const* d_in, const int* in_sizes, int n_in,
                              void* d_out, int out_size, void* d_ws, size_t ws_size,
                              hipStream_t stream) {
    (void)in_sizes; (void)n_in; (void)out_size; (void)ws_size;
    const float* xyz = (const float*)d_in[0];
    const float* features = (const float*)d_in[1];
    const float* w0 = (const float*)d_in[2];
    const float* bb0 = (const float*)d_in[3];
    const float* g0 = (const float*)d_in[4];
    const float* be0 = (const float*)d_in[5];
    const float* m0 = (const float*)d_in[6];
    const float* v0 = (const float*)d_in[7];
    const float* w1 = (const float*)d_in[8];
    const float* bb1 = (const float*)d_in[9];
    const float* g1 = (const float*)d_in[10];
    const float* be1 = (const float*)d_in[11];
    const float* m1 = (const float*)d_in[12];
    const float* v1 = (const float*)d_in[13];
    const float* w2 = (const float*)d_in[14];
    const float* bb2 = (const float*)d_in[15];
    const float* g2 = (const float*)d_in[16];
    const float* be2 = (const float*)d_in[17];
    const float* m2 = (const float*)d_in[18];
    const float* v2 = (const float*)d_in[19];
    const float* c1w = (const float*)d_in[20];
    const float* c1b = (const float*)d_in[21];
    const float* g3 = (const float*)d_in[22];
    const float* be3 = (const float*)d_in[23];
    const float* m3 = (const float*)d_in[24];
    const float* v3 = (const float*)d_in[25];
    const float* c2w = (const float*)d_in[26];
    const float* c2b = (const float*)d_in[27];
    const float* g4 = (const float*)d_in[28];
    const float* be4 = (const float*)d_in[29];
    const float* m4 = (const float*)d_in[30];
    const float* v4 = (const float*)d_in[31];
    const float* c3w = (const float*)d_in[32];
    const float* c3b = (const float*)d_in[33];
    float* out = (float*)d_out;

    // workspace layout (byte offsets, 16B aligned)
    char* ws = (char*)d_ws;
    float* nxyz = (float*)(ws + 0);                            // 12288 f32   -> 49152
    float* scbi = (float*)(ws + 49152);                        // 768 f32     -> 52224
    float* scbiH = (float*)(ws + 52224);                       // 592 f32     -> 54592
    unsigned short* Wf0 = (unsigned short*)(ws + 54592);       // 36864 bf    -> 128320
    unsigned short* Wf1 = (unsigned short*)(ws + 128320);      // 16384 bf    -> 161088
    unsigned short* Wf2 = (unsigned short*)(ws + 161088);      // 16384 bf    -> 193856
    unsigned short* Wfc1 = (unsigned short*)(ws + 193856);     // 16384 bf    -> 226624
    unsigned short* Wfc2 = (unsigned short*)(ws + 226624);     // 16384 bf    -> 259392
    unsigned short* Wfc3 = (unsigned short*)(ws + 259392);     // 10240 bf    -> 279872
    unsigned short* pooledb = (unsigned short*)(ws + 279872);  // 524288 bf   -> 804160
    unsigned short* featT = (unsigned short*)(ws + 804160);    // 32*2048*256 bf16

    hipLaunchKernelGGL(fused_front_kernel, dim3(Bn + 8192 + 18), dim3(256), 0, stream,
                       xyz, features, nxyz, featT,
                       w0, bb0, g0, be0, m0, v0,
                       w1, bb1, g1, be1, m1, v1,
                       w2, bb2, g2, be2, m2, v2,
                       c1w, c1b, g3, be3, m3, v3,
                       c2w, c2b, g4, be4, m4, v4,
                       c3w, c3b,
                       Wf0, Wf1, Wf2, Wfc1, Wfc2, Wfc3, scbi, scbiH);
    hipLaunchKernelGGL(groupmlp_mfma_kernel, dim3(Bn * Sn / 4), dim3(256), 0, stream,
                       xyz, featT, nxyz, Wf0, Wf1, Wf2, scbi, pooledb);
    hipLaunchKernelGGL(head_mfma_kernel, dim3(Bn * Sn / 16), dim3(64), 0, stream,
                       pooledb, nxyz, Wfc1, Wfc2, Wfc3, scbiH, out);
}

// Round 10
// 279.874 us; speedup vs baseline: 1.1585x; 1.1585x over previous
//
#include <hip/hip_runtime.h>
#include <hip/hip_bf16.h>
#include <math.h>

#define Bn 32
#define Nn 2048
#define Cc 256
#define Sn 128
#define KK 16
#define H 128
#define OUTC 79
#define ODIM 124
#define KP1 288  // layer-1 K padded: 256 features + 3 xyz + 29 zeros

typedef __attribute__((ext_vector_type(8))) short short8;
typedef __attribute__((ext_vector_type(4))) float f32x4;
typedef unsigned long long ull;

__device__ __constant__ float MEANF[30] = {
    0.76584f, 1.398258f, 0.472728f,
    2.114256f, 1.6203f, 0.927272f,
    0.404671f, 1.071108f, 1.688889f,
    0.591958f, 0.552978f, 0.827272f,
    0.69519f, 1.346299f, 0.736364f,
    0.528526f, 1.002642f, 1.172878f,
    0.500618f, 0.632163f, 0.683424f,
    0.923508f, 1.867419f, 0.845495f,
    0.791118f, 1.279516f, 0.718182f,
    0.699104f, 0.454178f, 0.75625f};

__device__ __forceinline__ unsigned short f2bf(float f) {
    __hip_bfloat16 h = __float2bfloat16(f);
    return *reinterpret_cast<unsigned short*>(&h);
}

__device__ __forceinline__ ull umax64(ull a, ull b) { return a > b ? a : b; }

// u64 max across 64 lanes via DPP (VALU-only, no LDS-pipe latency).
// After the 6 steps lane 63 holds the wave max.
#define DPPMAX(CTRL, RM)                                                        \
    {                                                                           \
        const int nhi = __builtin_amdgcn_update_dpp(0, hi, CTRL, RM, 0xf, false); \
        const int nlo = __builtin_amdgcn_update_dpp(0, lo, CTRL, RM, 0xf, false); \
        const ull nk = ((ull)(unsigned)nhi << 32) | (unsigned)nlo;              \
        const ull ck = ((ull)(unsigned)hi << 32) | (unsigned)lo;                \
        if (nk > ck) { hi = nhi; lo = nlo; }                                    \
    }

// ---------------- fused FPS (blocks 0..31) + feature transpose (rest) ----------------
struct SmemFPS {
    float xs[Nn * 3];
    ull red[2][4];
    float nx[Sn * 3];
};
struct SmemT {
    float tile[64][33];
};
__global__ __launch_bounds__(256) void fps_transpose_kernel(const float* __restrict__ xyz,
                                                            const float* __restrict__ features,
                                                            float* __restrict__ new_xyz,
                                                            unsigned short* __restrict__ fT) {
    __shared__ __align__(16) char smem_raw[sizeof(SmemT) > sizeof(SmemFPS) ? sizeof(SmemT)
                                                                           : sizeof(SmemFPS)];
    const int bid = blockIdx.x;
    if (bid >= Bn) {
        // ---- transpose role ----
        SmemT* sm = (SmemT*)smem_raw;
        const int tb = bid - Bn;
        const int b = tb >> 8;
        const int rem = tb & 255;
        const int n0 = (rem & 63) * 32;
        const int c0 = (rem >> 6) * 64;
        const int tx = threadIdx.x & 31;
        const int ty = threadIdx.x >> 5;
        for (int i = ty; i < 64; i += 8)
            sm->tile[i][tx] = features[((size_t)b * Cc + (c0 + i)) * Nn + n0 + tx];
        __syncthreads();
        for (int n = ty; n < 32; n += 8) {
            const float lo = sm->tile[tx * 2 + 0][n];
            const float hi = sm->tile[tx * 2 + 1][n];
            const unsigned int v = (unsigned int)f2bf(lo) | ((unsigned int)f2bf(hi) << 16);
            *reinterpret_cast<unsigned int*>(&fT[((size_t)b * Nn + (n0 + n)) * Cc + c0 + tx * 2]) = v;
        }
        return;
    }
    // ---- FPS role ----
    {
#pragma clang fp contract(off)
        SmemFPS* sm = (SmemFPS*)smem_raw;
        float* xs = sm->xs;
        const int b = bid;
        const int t = threadIdx.x;
        const int lane = t & 63;
        const int wv = t >> 6;

        {
            float4* xs4 = (float4*)xs;
            const float4* src = (const float4*)(xyz + (size_t)b * Nn * 3);
            for (int i = t; i < Nn * 3 / 4; i += 256) xs4[i] = src[i];
        }
        __syncthreads();

        const int base = wv * 512 + lane;
        float px[8], py[8], pz[8], mind[8];
        int klo[8];
#pragma unroll
        for (int j = 0; j < 8; j++) {
            const int p = base + j * 64;
            px[j] = xs[p * 3 + 0];
            py[j] = xs[p * 3 + 1];
            pz[j] = xs[p * 3 + 2];
            mind[j] = 1e10f;
            klo[j] = 2047 - p;
        }
        float lx = xs[0], ly = xs[1], lz = xs[2];

        for (int it = 0; it < Sn; ++it) {
            if (t == 0) {
                sm->nx[it * 3 + 0] = lx;
                sm->nx[it * 3 + 1] = ly;
                sm->nx[it * 3 + 2] = lz;
            }
            ull kk[8];
#pragma unroll
            for (int j = 0; j < 8; j++) {
                const float dx = px[j] - lx;
                const float dy = py[j] - ly;
                const float dz = pz[j] - lz;
                const float dx2 = dx * dx;
                const float dy2 = dy * dy;
                const float dz2 = dz * dz;
                const float s01 = dx2 + dy2;
                const float d = s01 + dz2;
                const float m = fminf(mind[j], d);
                mind[j] = m;
                kk[j] = ((ull)__float_as_uint(m) << 32) | (unsigned int)klo[j];
            }
            ull k0 = umax64(kk[0], kk[1]);
            ull k1 = umax64(kk[2], kk[3]);
            ull k2 = umax64(kk[4], kk[5]);
            ull k3 = umax64(kk[6], kk[7]);
            k0 = umax64(k0, k1);
            k2 = umax64(k2, k3);
            const ull bk0 = umax64(k0, k2);

            // DPP wave max-reduce -> lane 63
            int hi = (int)(bk0 >> 32);
            int lo = (int)(bk0 & 0xffffffffull);
            DPPMAX(0x111, 0xf)  // row_shr:1
            DPPMAX(0x112, 0xf)  // row_shr:2
            DPPMAX(0x114, 0xf)  // row_shr:4
            DPPMAX(0x118, 0xf)  // row_shr:8  -> lane 15/31/47/63 = row max
            DPPMAX(0x142, 0xa)  // row_bcast15 -> rows 1,3
            DPPMAX(0x143, 0xc)  // row_bcast31 -> rows 2,3 -> lane 63 = wave max

            if (lane == 63)
                sm->red[it & 1][wv] = ((ull)(unsigned)hi << 32) | (unsigned)lo;
            __syncthreads();
            ull r0 = sm->red[it & 1][0];
            ull r1 = sm->red[it & 1][1];
            ull r2 = sm->red[it & 1][2];
            ull r3 = sm->red[it & 1][3];
            const ull bk = umax64(umax64(r0, r1), umax64(r2, r3));
            const int last = 2047 - (int)(bk & 0xffffffffull);
            lx = xs[last * 3 + 0];
            ly = xs[last * 3 + 1];
            lz = xs[last * 3 + 2];
        }
        __syncthreads();
        for (int i = t; i < Sn * 3; i += 256)
            new_xyz[(size_t)b * Sn * 3 + i] = sm->nx[i];
    }
}

// ---------------- prep: fold BN, build FRAGMENT-MAJOR bf16 weights ----------------
__device__ __forceinline__ float w0val(const float* __restrict__ w0, int n, int k) {
    if (k < 256) return w0[(3 + k) * H + n];
    if (k < 259) return w0[(k - 256) * H + n];
    return 0.0f;
}

__global__ __launch_bounds__(256) void prep_kernel(
    const float* __restrict__ w0, const float* __restrict__ bb0,
    const float* __restrict__ g0, const float* __restrict__ be0,
    const float* __restrict__ m0, const float* __restrict__ v0,
    const float* __restrict__ w1, const float* __restrict__ bb1,
    const float* __restrict__ g1, const float* __restrict__ be1,
    const float* __restrict__ m1, const float* __restrict__ v1,
    const float* __restrict__ w2, const float* __restrict__ bb2,
    const float* __restrict__ g2, const float* __restrict__ be2,
    const float* __restrict__ m2, const float* __restrict__ v2,
    const float* __restrict__ c1w, const float* __restrict__ c1b,
    const float* __restrict__ g3, const float* __restrict__ be3,
    const float* __restrict__ m3, const float* __restrict__ v3,
    const float* __restrict__ c2w, const float* __restrict__ c2b,
    const float* __restrict__ g4, const float* __restrict__ be4,
    const float* __restrict__ m4, const float* __restrict__ v4,
    const float* __restrict__ c3w, const float* __restrict__ c3b,
    unsigned short* __restrict__ Wf0, unsigned short* __restrict__ Wf1,
    unsigned short* __restrict__ Wf2, unsigned short* __restrict__ Wfc1,
    unsigned short* __restrict__ Wfc2, unsigned short* __restrict__ Wfc3,
    float* __restrict__ scbi, float* __restrict__ scbiH) {
    const int idx = blockIdx.x * 256 + threadIdx.x;

    if (idx < 4608) {
        const int kc = idx / 512;
        const int rem = idx & 511;
        const int nt = rem >> 6;
        const int lane = rem & 63;
        const int n = nt * 16 + (lane & 15);
        const int kb = kc * 32 + (lane >> 4) * 8;
        union { unsigned short u[8]; uint4 q; } P;
#pragma unroll
        for (int j = 0; j < 8; j++) P.u[j] = f2bf(w0val(w0, n, kb + j));
        ((uint4*)Wf0)[idx] = P.q;
    }
    if (idx < 2048) {
        const int kc = idx >> 9;
        const int rem = idx & 511;
        const int nt = rem >> 6;
        const int lane = rem & 63;
        const int n = nt * 16 + (lane & 15);
        const int kb = kc * 32 + (lane >> 4) * 8;
        union { unsigned short u[8]; uint4 q; } P1, P2, P3, P4;
#pragma unroll
        for (int j = 0; j < 8; j++) {
            const int k = kb + j;
            P1.u[j] = f2bf(w1[k * H + n]);
            P2.u[j] = f2bf(w2[k * H + n]);
            P3.u[j] = f2bf(c1w[k * H + n]);
            P4.u[j] = f2bf(c2w[k * H + n]);
        }
        ((uint4*)Wf1)[idx] = P1.q;
        ((uint4*)Wf2)[idx] = P2.q;
        ((uint4*)Wfc1)[idx] = P3.q;
        ((uint4*)Wfc2)[idx] = P4.q;
    }
    if (idx < 1280) {
        const int kc = idx / 320;
        const int rem = idx % 320;
        const int nt = rem / 64;
        const int lane = rem % 64;
        const int n = nt * 16 + (lane & 15);
        const int kb = kc * 32 + (lane >> 4) * 8;
        union { unsigned short u[8]; uint4 q; } P;
#pragma unroll
        for (int j = 0; j < 8; j++)
            P.u[j] = (n < OUTC) ? f2bf(c3w[(kb + j) * OUTC + n]) : (unsigned short)0;
        ((uint4*)Wfc3)[idx] = P.q;
    }
    if (idx < 128) {
        const float sc1 = g0[idx] / sqrtf(v0[idx] + 1e-5f);
        scbi[0 * 128 + idx] = sc1;
        scbi[1 * 128 + idx] = (bb0[idx] - m0[idx]) * sc1 + be0[idx];
        const float sc2 = g1[idx] / sqrtf(v1[idx] + 1e-5f);
        scbi[2 * 128 + idx] = sc2;
        scbi[3 * 128 + idx] = (bb1[idx] - m1[idx]) * sc2 + be1[idx];
        const float sc3 = g2[idx] / sqrtf(v2[idx] + 1e-5f);
        scbi[4 * 128 + idx] = sc3;
        scbi[5 * 128 + idx] = (bb2[idx] - m2[idx]) * sc3 + be2[idx];
        const float sA = g3[idx] / sqrtf(v3[idx] + 1e-5f);
        scbiH[0 * 128 + idx] = sA;
        scbiH[1 * 128 + idx] = (c1b[idx] - m3[idx]) * sA + be3[idx];
        const float sB = g4[idx] / sqrtf(v4[idx] + 1e-5f);
        scbiH[2 * 128 + idx] = sB;
        scbiH[3 * 128 + idx] = (c2b[idx] - m4[idx]) * sB + be4[idx];
    }
    if (idx < 80) scbiH[512 + idx] = (idx < OUTC) ? c3b[idx] : 0.0f;
}

// ---------------- grouped MLP via MFMA, ball-query fused: one wave per (b,s) ----------------
#define YSTR 136  // LDS row stride in bf16 units (272B, 16B-aligned)
__global__ __launch_bounds__(256) void groupmlp_mfma_kernel(
    const float* __restrict__ xyz, const unsigned short* __restrict__ featT,
    const float* __restrict__ new_xyz,
    const unsigned short* __restrict__ Wf0, const unsigned short* __restrict__ Wf1,
    const unsigned short* __restrict__ Wf2, const float* __restrict__ scbi,
    unsigned short* __restrict__ pooledb) {
    const int wv = threadIdx.x >> 6;
    const int lane = threadIdx.x & 63;
    const int bs = blockIdx.x * 4 + wv;
    const int b = bs >> 7;
    const int mrow = lane & 15;
    const int quad = lane >> 4;

    __shared__ unsigned short ylds_all[4][16 * YSTR];
    __shared__ int sbuf[4][16];
    unsigned short* ylds = &ylds_all[wv][0];

    // ---- fused ball query ----
    const float cx = new_xyz[bs * 3 + 0];
    const float cy = new_xyz[bs * 3 + 1];
    const float cz = new_xyz[bs * 3 + 2];
    int basec = 0;
    {
#pragma clang fp contract(off)
        for (int c0 = 0; c0 < Nn && basec < KK; c0 += 64) {
            const int p = c0 + lane;
            const float dx = xyz[((size_t)b * Nn + p) * 3 + 0] - cx;
            const float dy = xyz[((size_t)b * Nn + p) * 3 + 1] - cy;
            const float dz = xyz[((size_t)b * Nn + p) * 3 + 2] - cz;
            const float dx2 = dx * dx;
            const float dy2 = dy * dy;
            const float dz2 = dz * dz;
            const float s01 = dx2 + dy2;
            const float d2 = s01 + dz2;
            const bool q = d2 < 0.09f;
            const ull mask = __ballot(q);
            const int prefix = __popcll(mask & ((1ull << lane) - 1ull));
            const int slot = basec + prefix;
            if (q && slot < KK) sbuf[wv][slot] = p;
            basec += __popcll(mask);
        }
    }
    const int cnt = basec < KK ? basec : KK;
    const int p = sbuf[wv][mrow < cnt ? mrow : 0];

    const short8* arow = reinterpret_cast<const short8*>(featT + ((size_t)(b * Nn + p)) * Cc);

    short8 a1x = {0, 0, 0, 0, 0, 0, 0, 0};
    {
        const float fx = xyz[((size_t)(b * Nn + p)) * 3 + 0];
        const float fy = xyz[((size_t)(b * Nn + p)) * 3 + 1];
        const float fz = xyz[((size_t)(b * Nn + p)) * 3 + 2];
        if (quad == 0) {
            a1x.s0 = (short)f2bf((fx - cx) / 0.3f);
            a1x.s1 = (short)f2bf((fy - cy) / 0.3f);
            a1x.s2 = (short)f2bf((fz - cz) / 0.3f);
        }
    }

    const short8* wf0 = reinterpret_cast<const short8*>(Wf0);
    const short8* wf1 = reinterpret_cast<const short8*>(Wf1);
    const short8* wf2 = reinterpret_cast<const short8*>(Wf2);
    const short8* yv = reinterpret_cast<const short8*>(ylds);

    f32x4 acc[8] = {};

    // ---- layer 1: K = 288 ----
    {
        short8 acur = arow[quad];
        short8 anxt;
        short8 bcur[8], bnxt[8];
#pragma unroll
        for (int nt = 0; nt < 8; nt++)
            bcur[nt] = wf0[nt * 64 + lane];
        for (int kc = 0; kc < 9; kc++) {
            if (kc < 8) {
                if (kc < 7) anxt = arow[(kc + 1) * 4 + quad];
                else anxt = a1x;
#pragma unroll
                for (int nt = 0; nt < 8; nt++)
                    bnxt[nt] = wf0[((kc + 1) * 8 + nt) * 64 + lane];
            }
#pragma unroll
            for (int nt = 0; nt < 8; nt++)
                acc[nt] = __builtin_amdgcn_mfma_f32_16x16x32_bf16(acur, bcur[nt], acc[nt], 0, 0, 0);
            acur = anxt;
#pragma unroll
            for (int nt = 0; nt < 8; nt++) bcur[nt] = bnxt[nt];
        }
    }
#pragma unroll
    for (int nt = 0; nt < 8; nt++) {
        const int n = nt * 16 + mrow;
        const float sc = scbi[0 * 128 + n];
        const float bi = scbi[1 * 128 + n];
#pragma unroll
        for (int r = 0; r < 4; r++) {
            const float z = fmaxf(acc[nt][r] * sc + bi, 0.0f);
            ylds[(quad * 4 + r) * YSTR + n] = f2bf(z);
        }
    }

    // ---- layer 2: K = 128 ----
#pragma unroll
    for (int nt = 0; nt < 8; nt++) acc[nt] = (f32x4){0.f, 0.f, 0.f, 0.f};
    {
        short8 acur = yv[mrow * (YSTR / 8) + quad];
        short8 anxt;
        short8 bcur[8], bnxt[8];
#pragma unroll
        for (int nt = 0; nt < 8; nt++)
            bcur[nt] = wf1[nt * 64 + lane];
        for (int kc = 0; kc < 4; kc++) {
            if (kc < 3) {
                anxt = yv[mrow * (YSTR / 8) + (kc + 1) * 4 + quad];
#pragma unroll
                for (int nt = 0; nt < 8; nt++)
                    bnxt[nt] = wf1[((kc + 1) * 8 + nt) * 64 + lane];
            }
#pragma unroll
            for (int nt = 0; nt < 8; nt++)
                acc[nt] = __builtin_amdgcn_mfma_f32_16x16x32_bf16(acur, bcur[nt], acc[nt], 0, 0, 0);
            acur = anxt;
#pragma unroll
            for (int nt = 0; nt < 8; nt++) bcur[nt] = bnxt[nt];
        }
    }
#pragma unroll
    for (int nt = 0; nt < 8; nt++) {
        const int n = nt * 16 + mrow;
        const float sc = scbi[2 * 128 + n];
        const float bi = scbi[3 * 128 + n];
#pragma unroll
        for (int r = 0; r < 4; r++) {
            const float z = fmaxf(acc[nt][r] * sc + bi, 0.0f);
            ylds[(quad * 4 + r) * YSTR + n] = f2bf(z);
        }
    }

    // ---- layer 3: K = 128, then BN+relu+maxpool over m ----
#pragma unroll
    for (int nt = 0; nt < 8; nt++) acc[nt] = (f32x4){0.f, 0.f, 0.f, 0.f};
    {
        short8 acur = yv[mrow * (YSTR / 8) + quad];
        short8 anxt;
        short8 bcur[8], bnxt[8];
#pragma unroll
        for (int nt = 0; nt < 8; nt++)
            bcur[nt] = wf2[nt * 64 + lane];
        for (int kc = 0; kc < 4; kc++) {
            if (kc < 3) {
                anxt = yv[mrow * (YSTR / 8) + (kc + 1) * 4 + quad];
#pragma unroll
                for (int nt = 0; nt < 8; nt++)
                    bnxt[nt] = wf2[((kc + 1) * 8 + nt) * 64 + lane];
            }
#pragma unroll
            for (int nt = 0; nt < 8; nt++)
                acc[nt] = __builtin_amdgcn_mfma_f32_16x16x32_bf16(acur, bcur[nt], acc[nt], 0, 0, 0);
            acur = anxt;
#pragma unroll
            for (int nt = 0; nt < 8; nt++) bcur[nt] = bnxt[nt];
        }
    }
#pragma unroll
    for (int nt = 0; nt < 8; nt++) {
        const int n = nt * 16 + mrow;
        const float sc = scbi[4 * 128 + n];
        const float bi = scbi[5 * 128 + n];
        float vmax = 0.0f;
#pragma unroll
        for (int r = 0; r < 4; r++)
            vmax = fmaxf(vmax, acc[nt][r] * sc + bi);
        vmax = fmaxf(vmax, __shfl_xor(vmax, 16));
        vmax = fmaxf(vmax, __shfl_xor(vmax, 32));
        if (quad == 0) pooledb[(size_t)bs * H + n] = f2bf(vmax);
    }
}

// ---------------- FC head via MFMA: one wave per 16 proposals + fused decode ----------------
__global__ __launch_bounds__(64) void head_mfma_kernel(
    const unsigned short* __restrict__ pooledb, const float* __restrict__ new_xyz,
    const unsigned short* __restrict__ Wfc1, const unsigned short* __restrict__ Wfc2,
    const unsigned short* __restrict__ Wfc3, const float* __restrict__ scbiH,
    float* __restrict__ out) {
    const int lane = threadIdx.x;
    const int row0 = blockIdx.x * 16;
    const int mrow = lane & 15;
    const int quad = lane >> 4;

    __shared__ unsigned short ylds[16 * YSTR];
    __shared__ float flds[16 * 84];

    const short8* ar = reinterpret_cast<const short8*>(pooledb + (size_t)(row0 + mrow) * H);
    const short8* w1h = reinterpret_cast<const short8*>(Wfc1);
    const short8* w2h = reinterpret_cast<const short8*>(Wfc2);
    const short8* w3h = reinterpret_cast<const short8*>(Wfc3);
    const short8* yv = reinterpret_cast<const short8*>(ylds);

    f32x4 acc[8] = {};
#pragma unroll
    for (int kc = 0; kc < 4; kc++) {
        const short8 a = ar[kc * 4 + quad];
#pragma unroll
        for (int nt = 0; nt < 8; nt++) {
            const short8 bf = w1h[(kc * 8 + nt) * 64 + lane];
            acc[nt] = __builtin_amdgcn_mfma_f32_16x16x32_bf16(a, bf, acc[nt], 0, 0, 0);
        }
    }
#pragma unroll
    for (int nt = 0; nt < 8; nt++) {
        const int n = nt * 16 + mrow;
        const float sc = scbiH[0 * 128 + n];
        const float bi = scbiH[1 * 128 + n];
#pragma unroll
        for (int r = 0; r < 4; r++) {
            const float z = fmaxf(acc[nt][r] * sc + bi, 0.0f);
            ylds[(quad * 4 + r) * YSTR + n] = f2bf(z);
        }
    }

#pragma unroll
    for (int nt = 0; nt < 8; nt++) acc[nt] = (f32x4){0.f, 0.f, 0.f, 0.f};
#pragma unroll
    for (int kc = 0; kc < 4; kc++) {
        const short8 a = yv[mrow * (YSTR / 8) + kc * 4 + quad];
#pragma unroll
        for (int nt = 0; nt < 8; nt++) {
            const short8 bf = w2h[(kc * 8 + nt) * 64 + lane];
            acc[nt] = __builtin_amdgcn_mfma_f32_16x16x32_bf16(a, bf, acc[nt], 0, 0, 0);
        }
    }
#pragma unroll
    for (int nt = 0; nt < 8; nt++) {
        const int n = nt * 16 + mrow;
        const float sc = scbiH[2 * 128 + n];
        const float bi = scbiH[3 * 128 + n];
#pragma unroll
        for (int r = 0; r < 4; r++) {
            const float z = fmaxf(acc[nt][r] * sc + bi, 0.0f);
            ylds[(quad * 4 + r) * YSTR + n] = f2bf(z);
        }
    }

    f32x4 acc3[5] = {};
#pragma unroll
    for (int kc = 0; kc < 4; kc++) {
        const short8 a = yv[mrow * (YSTR / 8) + kc * 4 + quad];
#pragma unroll
        for (int nt = 0; nt < 5; nt++) {
            const short8 bf = w3h[(kc * 5 + nt) * 64 + lane];
            acc3[nt] = __builtin_amdgcn_mfma_f32_16x16x32_bf16(a, bf, acc3[nt], 0, 0, 0);
        }
    }
#pragma unroll
    for (int nt = 0; nt < 5; nt++) {
        const int n = nt * 16 + mrow;
        const float bi = scbiH[512 + n];
#pragma unroll
        for (int r = 0; r < 4; r++)
            flds[(quad * 4 + r) * 84 + n] = acc3[nt][r] + bi;
    }

    for (int m = 0; m < 16; m++) {
        const int row = row0 + m;
        const float* net = &flds[m * 84];
        const float* nz = new_xyz + (size_t)row * 3;
#pragma unroll
        for (int jj = 0; jj < 2; jj++) {
            const int j = lane + jj * 64;
            if (j < ODIM) {
                float val;
                if (j < 3) val = nz[j];
                else if (j < 5) val = net[j - 3];
                else if (j < 8) val = nz[j - 5] + net[2 + (j - 5)];
                else if (j < 20) val = net[5 + (j - 8)];
                else if (j < 32) val = net[17 + (j - 20)];
                else if (j < 44) val = net[17 + (j - 32)] * (float)(3.14159265358979323846 / 12.0);
                else if (j < 54) val = net[29 + (j - 44)];
                else if (j < 84) val = net[39 + (j - 54)];
                else if (j < 114) val = net[39 + (j - 84)] * MEANF[j - 84];
                else val = net[69 + (j - 114)];
                out[(size_t)row * ODIM + j] = val;
            }
        }
    }
}

extern "C" void kernel_launch(void* const* d_in, const int* in_sizes, int n_in,
                              void* d_out, int out_size, void* d_ws, size_t ws_size,
                              hipStream_t stream) {
    (void)in_sizes; (void)n_in; (void)out_size; (void)ws_size;
    const float* xyz = (const float*)d_in[0];
    const float* features = (const float*)d_in[1];
    const float* w0 = (const float*)d_in[2];
    const float* bb0 = (const float*)d_in[3];
    const float* g0 = (const float*)d_in[4];
    const float* be0 = (const float*)d_in[5];
    const float* m0 = (const float*)d_in[6];
    const float* v0 = (const float*)d_in[7];
    const float* w1 = (const float*)d_in[8];
    const float* bb1 = (const float*)d_in[9];
    const float* g1 = (const float*)d_in[10];
    const float* be1 = (const float*)d_in[11];
    const float* m1 = (const float*)d_in[12];
    const float* v1 = (const float*)d_in[13];
    const float* w2 = (const float*)d_in[14];
    const float* bb2 = (const float*)d_in[15];
    const float* g2 = (const float*)d_in[16];
    const float* be2 = (const float*)d_in[17];
    const float* m2 = (const float*)d_in[18];
    const float* v2 = (const float*)d_in[19];
    const float* c1w = (const float*)d_in[20];
    const float* c1b = (const float*)d_in[21];
    const float* g3 = (const float*)d_in[22];
    const float* be3 = (const float*)d_in[23];
    const float* m3 = (const float*)d_in[24];
    const float* v3 = (const float*)d_in[25];
    const float* c2w = (const float*)d_in[26];
    const float* c2b = (const float*)d_in[27];
    const float* g4 = (const float*)d_in[28];
    const float* be4 = (const float*)d_in[29];
    const float* m4 = (const float*)d_in[30];
    const float* v4 = (const float*)d_in[31];
    const float* c3w = (const float*)d_in[32];
    const float* c3b = (const float*)d_in[33];
    float* out = (float*)d_out;

    // workspace layout (byte offsets, 16B aligned)
    char* ws = (char*)d_ws;
    float* nxyz = (float*)(ws + 0);                            // 12288 f32   -> 49152
    float* scbi = (float*)(ws + 49152);                        // 768 f32     -> 52224
    float* scbiH = (float*)(ws + 52224);                       // 592 f32     -> 54592
    unsigned short* Wf0 = (unsigned short*)(ws + 54592);       // 36864 bf    -> 128320
    unsigned short* Wf1 = (unsigned short*)(ws + 128320);      // 16384 bf    -> 161088
    unsigned short* Wf2 = (unsigned short*)(ws + 161088);      // 16384 bf    -> 193856
    unsigned short* Wfc1 = (unsigned short*)(ws + 193856);     // 16384 bf    -> 226624
    unsigned short* Wfc2 = (unsigned short*)(ws + 226624);     // 16384 bf    -> 259392
    unsigned short* Wfc3 = (unsigned short*)(ws + 259392);     // 10240 bf    -> 279872
    unsigned short* pooledb = (unsigned short*)(ws + 279872);  // 524288 bf   -> 804160
    unsigned short* featT = (unsigned short*)(ws + 804160);    // 32*2048*256 bf16

    hipLaunchKernelGGL(prep_kernel, dim3(18), dim3(256), 0, stream,
                       w0, bb0, g0, be0, m0, v0,
                       w1, bb1, g1, be1, m1, v1,
                       w2, bb2, g2, be2, m2, v2,
                       c1w, c1b, g3, be3, m3, v3,
                       c2w, c2b, g4, be4, m4, v4,
                       c3w, c3b,
                       Wf0, Wf1, Wf2, Wfc1, Wfc2, Wfc3, scbi, scbiH);
    hipLaunchKernelGGL(fps_transpose_kernel, dim3(Bn + Bn * 256), dim3(256), 0, stream,
                       xyz, features, nxyz, featT);
    hipLaunchKernelGGL(groupmlp_mfma_kernel, dim3(Bn * Sn / 4), dim3(256), 0, stream,
                       xyz, featT, nxyz, Wf0, Wf1, Wf2, scbi, pooledb);
    hipLaunchKernelGGL(head_mfma_kernel, dim3(Bn * Sn / 16), dim3(64), 0, stream,
                       pooledb, nxyz, Wfc1, Wfc2, Wfc3, scbiH, out);
}